// Round 5
// baseline (111.205 us; speedup 1.0000x reference)
//
#include <hip/hip_runtime.h>

// RaySamples: per-ray (K=128) exclusive scan of delta*density, then
//   T = exp(-acc_excl), w = T[k] - T[k+1]  (== alpha*T algebraically).
// Layout: K=128 fp32 = 2 rays per wave64 at one float4 per lane; rays are
// contiguous, so flat float4 index == coalesced access AND the ray
// boundary lands exactly on the lane-32 boundary -> segmented scan via
// __shfl_up(width=32). Chunk stride is a multiple of 32 quads, so every
// chunk's 32-lane segment maps to exactly one ray.
//
// Ledger: NT loads = -9 us regression (R3, inputs must stay cacheable).
//         2-chunk + NT stores = +2 us win (R4, 112.0 -> 110.0).
// This revision: 4 chunks/thread (single variable vs R4) — 8 loads
// hoisted ahead of the serialized ds_bpermute scan chains, 4 chains
// interleaved for ILP. Kernel moves 128 MiB compulsory HBM traffic
// (~20.4 us floor @ 6.3 TB/s); currently ~24.5 us.

typedef float f4 __attribute__((ext_vector_type(4)));

__global__ __launch_bounds__(256) void RaySamples_34454227648765_kernel(
    const float* __restrict__ dens, const float* __restrict__ delt,
    float* __restrict__ outw, float* __restrict__ outT, int n4)
{
    const int stride = gridDim.x * blockDim.x;           // in float4 units
    const int i0 = blockIdx.x * blockDim.x + threadIdx.x;
    const int lane = threadIdx.x & 31;

    const f4* __restrict__ d4 = reinterpret_cast<const f4*>(dens);
    const f4* __restrict__ l4 = reinterpret_cast<const f4*>(delt);
    f4* __restrict__ w4 = reinterpret_cast<f4*>(outw);
    f4* __restrict__ t4 = reinterpret_cast<f4*>(outT);

    // stride and n4 are multiples of 32 -> branches are segment-uniform.
    if (i0 + 3 * stride < n4) {
        // ---- fast path: 4 chunks, all loads issued before any compute ----
        f4 dv[4], lv[4];
        #pragma unroll
        for (int c = 0; c < 4; ++c) {
            dv[c] = d4[i0 + c * stride];     // plain loads: cacheable
            lv[c] = l4[i0 + c * stride];
        }

        float dd[4][4], s[4], inc[4];
        #pragma unroll
        for (int c = 0; c < 4; ++c) {
            dd[c][0] = dv[c].x * lv[c].x;
            dd[c][1] = dv[c].y * lv[c].y;
            dd[c][2] = dv[c].z * lv[c].z;
            dd[c][3] = dv[c].w * lv[c].w;
            s[c] = dd[c][0] + dd[c][1] + dd[c][2] + dd[c][3];
            inc[c] = s[c];
        }

        // 4 independent inclusive scans over the 32-lane ray segments;
        // chains interleave to cover ds_bpermute latency.
        #pragma unroll
        for (int off = 1; off < 32; off <<= 1) {
            #pragma unroll
            for (int c = 0; c < 4; ++c) {
                float v = __shfl_up(inc[c], off, 32);
                inc[c] += (lane >= off) ? v : 0.0f;
            }
        }

        #pragma unroll
        for (int c = 0; c < 4; ++c) {
            float a0 = inc[c] - s[c];                 // exclusive depth
            float a1 = a0 + dd[c][0];
            float a2 = a1 + dd[c][1];
            float a3 = a2 + dd[c][2];
            float a4 = a3 + dd[c][3];
            float t0 = __expf(-a0), t1 = __expf(-a1), t2 = __expf(-a2),
                  t3 = __expf(-a3), t4v = __expf(-a4);
            f4 W; W.x = t0 - t1; W.y = t1 - t2; W.z = t2 - t3; W.w = t3 - t4v;
            f4 T; T.x = t0; T.y = t1; T.z = t2; T.w = t3;
            __builtin_nontemporal_store(W, w4 + i0 + c * stride);
            __builtin_nontemporal_store(T, t4 + i0 + c * stride);
        }
    } else {
        // ---- generic tail (not taken for this shape; robustness) ----
        #pragma unroll
        for (int c = 0; c < 4; ++c) {
            int i = i0 + c * stride;
            if (i < n4) {
                const f4 d  = d4[i];
                const f4 dl = l4[i];
                float dd0 = d.x * dl.x, dd1 = d.y * dl.y,
                      dd2 = d.z * dl.z, dd3 = d.w * dl.w;
                float sc = dd0 + dd1 + dd2 + dd3;
                float in = sc;
                #pragma unroll
                for (int off = 1; off < 32; off <<= 1) {
                    float v = __shfl_up(in, off, 32);
                    in += (lane >= off) ? v : 0.0f;
                }
                float a0 = in - sc;
                float a1 = a0 + dd0, a2 = a1 + dd1, a3 = a2 + dd2,
                      a4 = a3 + dd3;
                float t0 = __expf(-a0), t1 = __expf(-a1), t2 = __expf(-a2),
                      t3 = __expf(-a3), t4v = __expf(-a4);
                f4 W; W.x = t0 - t1; W.y = t1 - t2; W.z = t2 - t3; W.w = t3 - t4v;
                f4 T; T.x = t0; T.y = t1; T.z = t2; T.w = t3;
                __builtin_nontemporal_store(W, w4 + i);
                __builtin_nontemporal_store(T, t4 + i);
            }
        }
    }
}

extern "C" void kernel_launch(void* const* d_in, const int* in_sizes, int n_in,
                              void* d_out, int out_size, void* d_ws, size_t ws_size,
                              hipStream_t stream) {
    const float* dens = (const float*)d_in[0];   // densities [N,K,1] fp32
    const float* delt = (const float*)d_in[1];   // deltas    [N,K,1] fp32
    float* out = (float*)d_out;                  // [weights | transmittance]

    const int NK = in_sizes[0];                  // N*K = 8388608
    const int n4 = NK / 4;                       // float4 quads
    float* outw = out;
    float* outT = out + NK;

    const int block = 256;
    const int threads_needed = (n4 + 3) / 4;     // 4 chunks per thread
    const int grid = (threads_needed + block - 1) / block;   // 2048 blocks
    RaySamples_34454227648765_kernel<<<grid, block, 0, stream>>>(
        dens, delt, outw, outT, n4);
}

// Round 6
// 108.363 us; speedup vs baseline: 1.0262x; 1.0262x over previous
//
#include <hip/hip_runtime.h>

// RaySamples: per-ray (K=128) exclusive scan of delta*density, then
//   T = exp(-acc_excl), w = T[k] - T[k+1]  (== alpha*T algebraically).
// Layout trick: K=128 fp32 = 2 rays per wave64 at one float4 per lane;
// rays are contiguous, so flat float4 index == coalesced access AND the
// ray boundary lands exactly on the lane-32 boundary -> segmented scan
// via __shfl_up(width=32).
//
// Ledger (end-to-end dur_us; graph includes ~85.5 us of harness fills):
//   R0 baseline 1-chunk plain:            112.0
//   R3 2-chunk + NT loads+stores:         120.7  (NT loads kill L3 input hits)
//   R4 2-chunk + NT stores only:          110.0  <- BEST, this kernel
//   R5 4-chunk + NT stores only:          111.2  (MLP exhausted)
// Kernel dispatch ~24.5 us for 128 MiB mixed r/w = 5.5 TB/s effective,
// ~87% of the write-only fill rate (6.35 TB/s) — at the practical
// mixed-stream HBM ceiling. Inputs must use PLAIN loads (L3-cacheable);
// outputs use NT stores (re-poisoned every iteration, zero reuse).

typedef float f4 __attribute__((ext_vector_type(4)));

__global__ __launch_bounds__(256) void RaySamples_34454227648765_kernel(
    const float* __restrict__ dens, const float* __restrict__ delt,
    float* __restrict__ outw, float* __restrict__ outT, int n4)
{
    const int stride = gridDim.x * blockDim.x;           // in float4 units
    const int i0 = blockIdx.x * blockDim.x + threadIdx.x;
    const int i1 = i0 + stride;
    const int lane = threadIdx.x & 31;

    const f4* __restrict__ d4 = reinterpret_cast<const f4*>(dens);
    const f4* __restrict__ l4 = reinterpret_cast<const f4*>(delt);
    f4* __restrict__ w4 = reinterpret_cast<f4*>(outw);
    f4* __restrict__ t4 = reinterpret_cast<f4*>(outT);

    // n4 and stride are both multiples of 32, so the (i1 < n4) branch is
    // uniform across each 32-lane scan segment.
    if (i1 < n4) {
        // Plain (cacheable) loads — L3 serves these across iterations.
        const f4 dA = d4[i0];
        const f4 lA = l4[i0];
        const f4 dB = d4[i1];
        const f4 lB = l4[i1];

        float A0 = dA.x * lA.x, A1 = dA.y * lA.y,
              A2 = dA.z * lA.z, A3 = dA.w * lA.w;
        float B0 = dB.x * lB.x, B1 = dB.y * lB.y,
              B2 = dB.z * lB.z, B3 = dB.w * lB.w;

        float sA = A0 + A1 + A2 + A3;   // lane totals
        float sB = B0 + B1 + B2 + B3;

        // Two independent inclusive scans across the 32-lane ray segments;
        // chains interleave for ILP over the ds_bpermute latency.
        float incA = sA, incB = sB;
        #pragma unroll
        for (int off = 1; off < 32; off <<= 1) {
            float vA = __shfl_up(incA, off, 32);
            float vB = __shfl_up(incB, off, 32);
            incA += (lane >= off) ? vA : 0.0f;
            incB += (lane >= off) ? vB : 0.0f;
        }

        float aA0 = incA - sA;          // exclusive optical depth
        float aA1 = aA0 + A0, aA2 = aA1 + A1, aA3 = aA2 + A2, aA4 = aA3 + A3;
        float aB0 = incB - sB;
        float aB1 = aB0 + B0, aB2 = aB1 + B1, aB3 = aB2 + B2, aB4 = aB3 + B3;

        float tA0 = __expf(-aA0), tA1 = __expf(-aA1), tA2 = __expf(-aA2),
              tA3 = __expf(-aA3), tA4 = __expf(-aA4);
        float tB0 = __expf(-aB0), tB1 = __expf(-aB1), tB2 = __expf(-aB2),
              tB3 = __expf(-aB3), tB4 = __expf(-aB4);

        f4 WA; WA.x = tA0 - tA1; WA.y = tA1 - tA2; WA.z = tA2 - tA3; WA.w = tA3 - tA4;
        f4 TA; TA.x = tA0; TA.y = tA1; TA.z = tA2; TA.w = tA3;
        f4 WB; WB.x = tB0 - tB1; WB.y = tB1 - tB2; WB.z = tB2 - tB3; WB.w = tB3 - tB4;
        f4 TB; TB.x = tB0; TB.y = tB1; TB.z = tB2; TB.w = tB3;

        __builtin_nontemporal_store(WA, w4 + i0);
        __builtin_nontemporal_store(TA, t4 + i0);
        __builtin_nontemporal_store(WB, w4 + i1);
        __builtin_nontemporal_store(TB, t4 + i1);
    } else if (i0 < n4) {
        // Generic tail (never taken for N*K divisible by 8*blockDim; kept
        // for shape robustness). Segment-uniform because n4 % 32 == 0.
        const f4 d  = d4[i0];
        const f4 dl = l4[i0];

        float dd0 = d.x * dl.x, dd1 = d.y * dl.y,
              dd2 = d.z * dl.z, dd3 = d.w * dl.w;
        float s = dd0 + dd1 + dd2 + dd3;
        float inc = s;
        #pragma unroll
        for (int off = 1; off < 32; off <<= 1) {
            float v = __shfl_up(inc, off, 32);
            inc += (lane >= off) ? v : 0.0f;
        }
        float a0 = inc - s;
        float a1 = a0 + dd0, a2 = a1 + dd1, a3 = a2 + dd2, a4 = a3 + dd3;
        float t0 = __expf(-a0), t1 = __expf(-a1), t2 = __expf(-a2),
              t3 = __expf(-a3), t4v = __expf(-a4);
        f4 W; W.x = t0 - t1; W.y = t1 - t2; W.z = t2 - t3; W.w = t3 - t4v;
        f4 T; T.x = t0; T.y = t1; T.z = t2; T.w = t3;
        __builtin_nontemporal_store(W, w4 + i0);
        __builtin_nontemporal_store(T, t4 + i0);
    }
}

extern "C" void kernel_launch(void* const* d_in, const int* in_sizes, int n_in,
                              void* d_out, int out_size, void* d_ws, size_t ws_size,
                              hipStream_t stream) {
    const float* dens = (const float*)d_in[0];   // densities [N,K,1] fp32
    const float* delt = (const float*)d_in[1];   // deltas    [N,K,1] fp32
    float* out = (float*)d_out;                  // [weights | transmittance]

    const int NK = in_sizes[0];                  // N*K = 8388608
    const int n4 = NK / 4;                       // float4 quads
    float* outw = out;
    float* outT = out + NK;

    const int block = 256;
    const int threads_needed = (n4 + 1) / 2;     // 2 chunks per thread
    const int grid = (threads_needed + block - 1) / block;   // 4096 blocks
    RaySamples_34454227648765_kernel<<<grid, block, 0, stream>>>(
        dens, delt, outw, outT, n4);
}